// Round 8
// baseline (1416.091 us; speedup 1.0000x reference)
//
#include <hip/hip_runtime.h>
#include <math.h>

#define DD 512
#define NBLKA 400

#define PM 128          // prefilter tile rows
#define PN 128          // prefilter tile cols
#define KB 32           // k-chunk (one MFMA K per chunk)
#define ASTRIDE 40      // shorts per LDS row: 32 + 8 pad (80 B, 16B-aligned)
#define CSPLIT 12       // column splits -> 79*12=948 blocks (~3.7/CU)
#define NC 16           // candidates kept per row per split
#define PBUF 8          // push buffer per row
#define NCTOT (CSPLIT*NC)   // 192 candidates per row total
#define KOUTMAX 16
#define RS_MARGIN 2e-4f     // rescore prune margin (bf16 score err bound ~3e-5)

typedef __attribute__((ext_vector_type(8))) short bf16x8;   // 8 bf16 = 4 VGPR
typedef __attribute__((ext_vector_type(4))) float f32x4;    // MFMA 16x16 accumulator

static __device__ __forceinline__ unsigned short f2bf(float f) {
    unsigned u = __float_as_uint(f);
    u += 0x7fff + ((u >> 16) & 1);      // round-to-nearest-even
    return (unsigned short)(u >> 16);
}

// ---------------- Kernel A1: partial column sums of x^2 (fp64, deterministic) ----------------
__global__ void colsum_partial(const float* __restrict__ x, double* __restrict__ partial,
                               int N, int rows_per_block) {
    int b = blockIdx.x;
    int t = threadIdx.x;
    int r0 = b * rows_per_block;
    int r1 = min(r0 + rows_per_block, N);
    double s0 = 0.0, s1 = 0.0;
    for (int r = r0; r < r1; ++r) {
        float v0 = x[(size_t)r * DD + t];
        float v1 = x[(size_t)r * DD + t + 256];
        s0 += (double)v0 * (double)v0;
        s1 += (double)v1 * (double)v1;
    }
    partial[(size_t)b * DD + t]       = s0;
    partial[(size_t)b * DD + t + 256] = s1;
}

// ---------------- Kernel A2: rn=1/max(sqrt(s),eps) fp64, w=rn*rn fp64 ----------------
__global__ void colnorm_finish(const double* __restrict__ partial, double* __restrict__ rn,
                               double* __restrict__ w, int nblk) {
    int c = threadIdx.x;                 // 512 threads
    double s = 0.0;
    for (int b = 0; b < nblk; ++b) s += partial[(size_t)b * DD + c];
    double n = fmax(sqrt(s), 1e-12);
    double r = 1.0 / n;
    rn[c]  = r;
    w[c]   = r * r;
}

// ---------------- Kernel B: sq[i] fp64, sqf[i] fp32, xnbf[i][:] bf16 ----------------
__global__ void row_sq(const float* __restrict__ x, const double* __restrict__ rn,
                       double* __restrict__ sq, float* __restrict__ sqf,
                       unsigned short* __restrict__ xnbf, int N) {
    int i = blockIdx.x;
    int t = threadIdx.x;
    double a0 = (double)x[(size_t)i * DD + t]       * rn[t];
    double a1 = (double)x[(size_t)i * DD + t + 256] * rn[t + 256];
    xnbf[(size_t)i * DD + t]       = f2bf((float)a0);
    xnbf[(size_t)i * DD + t + 256] = f2bf((float)a1);
    double local = a0 * a0 + a1 * a1;
    __shared__ double red[256];
    red[t] = local;
    __syncthreads();
    for (int off = 128; off > 0; off >>= 1) {
        if (t < off) red[t] += red[t + off];
        __syncthreads();
    }
    if (t == 0) { sq[i] = red[0]; sqf[i] = (float)red[0]; }
}

// ---------------- Kernel C: bf16 MFMA 128x128 prefilter + per-row top-16 ----------------
__global__ __launch_bounds__(256, 3) void gemm_prefilter(
    const unsigned short* __restrict__ xnbf,
    const float* __restrict__ sqf, int* __restrict__ cand, float* __restrict__ cands,
    int N, int ntileN)
{
    __shared__ unsigned short A_s[PM][ASTRIDE];   // 10240 B
    __shared__ unsigned short B_s[PN][ASTRIDE];   // 10240 B
    __shared__ float Ls[PM][NC + 1];              // 8704 B
    __shared__ int   Li[PM][NC + 1];              // 8704 B
    __shared__ float Bsc[PM][PBUF + 1];           // 4608 B
    __shared__ int   Bid[PM][PBUF + 1];           // 4608 B
    __shared__ float sqi_s[PM];
    __shared__ float sqj_s[PN];
    __shared__ float thr_s[PM];
    __shared__ int   cnt_s[PM];
    __shared__ int   flag_s;                      // total ~48.2 KB -> 3 blocks/CU

    const int t      = threadIdx.x;
    const int lane15 = t & 15;
    const int quad   = (t >> 4) & 3;
    const int wave   = t >> 6;
    const int wr     = (wave >> 1) * 64;
    const int wc     = (wave & 1) * 64;
    const int row0   = blockIdx.x * PM;
    const int split  = blockIdx.y;

    const int sr0 = t >> 2, sc0 = t & 3;
    const int sr1 = sr0 + 64, sc1 = sc0;
    const int gi0 = row0 + sr0, gi1 = row0 + sr1;

    if (t == 0) flag_s = 0;
    if (t < PM) {
        int i = row0 + t;
        sqi_s[t] = (i < N) ? sqf[i] : 0.f;
        thr_s[t] = __builtin_inff();
        cnt_s[t] = 0;
        for (int m = 0; m < NC; ++m) { Ls[t][m] = __builtin_inff(); Li[t][m] = 0x7fffffff; }
    }

    f32x4 acc[4][4];

    for (int tile = split; tile < ntileN; tile += CSPLIT) {
        int col0 = tile * PN;
        int gj0 = col0 + sr0, gj1 = col0 + sr1;
        __syncthreads();
        if (t < PN) {
            int j = col0 + t;
            sqj_s[t] = (j < N) ? sqf[j] : __builtin_inff();
        }
#pragma unroll
        for (int mt = 0; mt < 4; ++mt)
#pragma unroll
            for (int nt = 0; nt < 4; ++nt)
                acc[mt][nt] = (f32x4){0.f, 0.f, 0.f, 0.f};

        const uint4 zv = make_uint4(0u, 0u, 0u, 0u);
        uint4 va0 = zv, va1 = zv, vb0 = zv, vb1 = zv;
        if (gi0 < N) va0 = *(const uint4*)&xnbf[(size_t)gi0 * DD + sc0 * 8];
        if (gi1 < N) va1 = *(const uint4*)&xnbf[(size_t)gi1 * DD + sc1 * 8];
        if (gj0 < N) vb0 = *(const uint4*)&xnbf[(size_t)gj0 * DD + sc0 * 8];
        if (gj1 < N) vb1 = *(const uint4*)&xnbf[(size_t)gj1 * DD + sc1 * 8];

#pragma unroll 1
        for (int kc = 0; kc < DD; kc += KB) {
            __syncthreads();
            *(uint4*)&A_s[sr0][(sc0 ^ (sr0 & 3)) * 8] = va0;
            *(uint4*)&A_s[sr1][(sc1 ^ (sr1 & 3)) * 8] = va1;
            *(uint4*)&B_s[sr0][(sc0 ^ (sr0 & 3)) * 8] = vb0;
            *(uint4*)&B_s[sr1][(sc1 ^ (sr1 & 3)) * 8] = vb1;
            if (kc + KB < DD) {
                int koff = kc + KB;
                va0 = zv; va1 = zv; vb0 = zv; vb1 = zv;
                if (gi0 < N) va0 = *(const uint4*)&xnbf[(size_t)gi0 * DD + koff + sc0 * 8];
                if (gi1 < N) va1 = *(const uint4*)&xnbf[(size_t)gi1 * DD + koff + sc1 * 8];
                if (gj0 < N) vb0 = *(const uint4*)&xnbf[(size_t)gj0 * DD + koff + sc0 * 8];
                if (gj1 < N) vb1 = *(const uint4*)&xnbf[(size_t)gj1 * DD + koff + sc1 * 8];
            }
            __syncthreads();
            bf16x8 af[4], bfg[4];
#pragma unroll
            for (int mt = 0; mt < 4; ++mt) {
                int r = wr + mt * 16 + lane15;
                af[mt] = *(const bf16x8*)&A_s[r][(quad ^ (r & 3)) * 8];
            }
#pragma unroll
            for (int nt = 0; nt < 4; ++nt) {
                int cl = wc + nt * 16 + lane15;
                bfg[nt] = *(const bf16x8*)&B_s[cl][(quad ^ (cl & 3)) * 8];
            }
#pragma unroll
            for (int mt = 0; mt < 4; ++mt)
#pragma unroll
                for (int nt = 0; nt < 4; ++nt)
                    acc[mt][nt] = __builtin_amdgcn_mfma_f32_16x16x32_bf16(
                        af[mt], bfg[nt], acc[mt][nt], 0, 0, 0);
        }
        // scores in place
#pragma unroll
        for (int mt = 0; mt < 4; ++mt)
#pragma unroll
            for (int nt = 0; nt < 4; ++nt)
#pragma unroll
                for (int reg = 0; reg < 4; ++reg) {
                    int rl = wr + mt * 16 + quad * 4 + reg;
                    int cl = wc + nt * 16 + lane15;
                    float g = acc[mt][nt][reg];
                    acc[mt][nt][reg] = (sqi_s[rl] - 2.f * g) + sqj_s[cl];
                }

        // push/merge rounds (race-free 4-barrier protocol, static acc indexing)
        unsigned long long done = 0ull;
        for (;;) {
#pragma unroll
            for (int mt = 0; mt < 4; ++mt)
#pragma unroll
                for (int reg = 0; reg < 4; ++reg) {
                    int rl = wr + mt * 16 + quad * 4 + reg;
                    float th = thr_s[rl];
#pragma unroll
                    for (int nt = 0; nt < 4; ++nt) {
                        const unsigned long long bit = 1ull << (mt * 16 + nt * 4 + reg);
                        if (!(done & bit)) {
                            float s = acc[mt][nt][reg];
                            int   j = col0 + wc + nt * 16 + lane15;
                            if (j < N && s <= th) {
                                int pos = atomicAdd(&cnt_s[rl], 1);
                                if (pos < PBUF) {
                                    Bsc[rl][pos] = s;
                                    Bid[rl][pos] = j;
                                    done |= bit;
                                }
                            } else {
                                done |= bit;
                            }
                        }
                    }
                }
            if (done != ~0ull) flag_s = 1;
            __syncthreads();                 // B1
            if (t < PM) {
                int c = cnt_s[t];
                if (c > PBUF) c = PBUF;
                cnt_s[t] = 0;
                for (int m = 0; m < c; ++m) {
                    float s = Bsc[t][m];
                    int   j = Bid[t][m];
                    float ws = Ls[t][NC - 1]; int wj = Li[t][NC - 1];
                    if (s < ws || (s == ws && j < wj)) {
                        int pos = NC - 1;
                        while (pos > 0) {
                            float ps = Ls[t][pos - 1]; int pj = Li[t][pos - 1];
                            if (!(s < ps || (s == ps && j < pj))) break;
                            Ls[t][pos] = ps; Li[t][pos] = pj;
                            --pos;
                        }
                        Ls[t][pos] = s; Li[t][pos] = j;
                    }
                }
                thr_s[t] = Ls[t][NC - 1];
            }
            __syncthreads();                 // B2
            int go = flag_s;
            __syncthreads();                 // B3
            if (t == 0) flag_s = 0;
            __syncthreads();                 // B4
            if (!go) break;
        }
    }
    // write this split's candidates (index + bf16 score)
    if (t < PM) {
        int i = row0 + t;
        if (i < N) {
            for (int m = 0; m < NC; ++m) {
                cand [(size_t)i * NCTOT + split * NC + m] = Li[t][m];
                cands[(size_t)i * NCTOT + split * NC + m] = Ls[t][m];
            }
        }
    }
}

// ---------------- Kernel D: pruned exact fp64 rescore + top-k ----------------
// One wave per row. Finds 9th-smallest bf16 score s9b (pivot counting),
// then fp64-rescores only candidates with score <= s9b + RS_MARGIN.
__global__ __launch_bounds__(256) void rescore_topk(
    const float* __restrict__ x, const double* __restrict__ w,
    const double* __restrict__ sq, const int* __restrict__ cand,
    const float* __restrict__ cands, int* __restrict__ out, int N, int k)
{
    __shared__ float Ssc[4][NCTOT];
    int lane = threadIdx.x & 63;
    int wid  = threadIdx.x >> 6;
    int i = blockIdx.x * 4 + wid;
    if (i >= N) return;

    size_t base = (size_t)i * NCTOT;
    // stage scores to LDS (same-wave visibility; no barrier needed)
#pragma unroll
    for (int z = 0; z < NCTOT / 64; ++z)
        Ssc[wid][lane + z * 64] = cands[base + lane + z * 64];

    // 9th-smallest via pivot counting: 3 pivots/lane covering all 192 slots
    float p0 = Ssc[wid][lane * 3 + 0];
    float p1 = Ssc[wid][lane * 3 + 1];
    float p2 = Ssc[wid][lane * 3 + 2];
    int c0 = 0, c1 = 0, c2 = 0;
    for (int m = 0; m < NCTOT; ++m) {
        float s = Ssc[wid][m];
        c0 += (s <= p0); c1 += (s <= p1); c2 += (s <= p2);
    }
    float best = __builtin_inff();
    if (c0 >= k) best = p0;
    if (c1 >= k && p1 < best) best = p1;
    if (c2 >= k && p2 < best) best = p2;
#pragma unroll
    for (int off = 32; off > 0; off >>= 1)
        best = fminf(best, __shfl_xor(best, off, 64));
    float cut = best + RS_MARGIN;

    double aw[8];
#pragma unroll
    for (int c = 0; c < 8; ++c) {
        int d = lane + 64 * c;
        aw[c] = (double)x[(size_t)i * DD + d] * w[d];
    }
    double sqi = sq[i];

    double bs[KOUTMAX];
    int    bj[KOUTMAX];
    for (int r = 0; r < k; ++r) { bs[r] = __builtin_inf(); bj[r] = 0x7fffffff; }

    for (int m = 0; m < NCTOT; ++m) {
        if (Ssc[wid][m] > cut) continue;          // wave-uniform skip
        int j = cand[base + m];
        double dot = 0.0;
        const float* p = &x[(size_t)j * DD + lane];
#pragma unroll
        for (int c = 0; c < 8; ++c)
            dot = fma(aw[c], (double)p[64 * c], dot);
#pragma unroll
        for (int off = 32; off > 0; off >>= 1)
            dot += __shfl_xor(dot, off, 64);
        double s = (sqi - 2.0 * dot) + sq[j];
        if (s < bs[k - 1] || (s == bs[k - 1] && j < bj[k - 1])) {
            int pos = k - 1;
            while (pos > 0) {
                double ps = bs[pos - 1]; int pj = bj[pos - 1];
                if (!(s < ps || (s == ps && j < pj))) break;
                bs[pos] = ps; bj[pos] = pj;
                --pos;
            }
            bs[pos] = s; bj[pos] = j;
        }
    }
    if (lane == 0) {
        for (int r = 0; r < k; ++r) {
            out[(size_t)i * k + r]                 = bj[r];
            out[(size_t)N * k + (size_t)i * k + r] = i;
        }
    }
}

extern "C" void kernel_launch(void* const* d_in, const int* in_sizes, int n_in,
                              void* d_out, int out_size, void* d_ws, size_t ws_size,
                              hipStream_t stream) {
    const float* x = (const float*)d_in[0];
    int N = in_sizes[0] / DD;            // 10000
    int k = out_size / (2 * N);          // 9
    if (k > KOUTMAX) k = KOUTMAX;

    char* ws = (char*)d_ws;
    double*         partial = (double*)ws;                       // 400*512*8 = 1638400 B
    double*         rn      = (double*)(ws + 1638400);           // 4096 B
    double*         w       = (double*)(ws + 1642496);           // 4096 B
    double*         sq      = (double*)(ws + 1646592);           // 80000 B
    float*          sqf     = (float*) (ws + 1726592);           // 40000 B
    unsigned short* xnbf    = (unsigned short*)(ws + 1766592);   // N*512*2 = 10.24 MB
    int*            cand    = (int*)   (ws + 12006592);          // N*192*4 = 7.68 MB
    float*          cands   = (float*) (ws + 19686592);          // N*192*4 = 7.68 MB

    int rpb = (N + NBLKA - 1) / NBLKA;
    hipLaunchKernelGGL(colsum_partial, dim3(NBLKA), dim3(256), 0, stream, x, partial, N, rpb);
    hipLaunchKernelGGL(colnorm_finish, dim3(1), dim3(512), 0, stream, partial, rn, w, NBLKA);
    hipLaunchKernelGGL(row_sq, dim3(N), dim3(256), 0, stream, x, rn, sq, sqf, xnbf, N);

    int nrow = (N + PM - 1) / PM;        // 79
    int ncol = (N + PN - 1) / PN;        // 79
    hipLaunchKernelGGL(gemm_prefilter, dim3(nrow, CSPLIT), dim3(256), 0, stream,
                       xnbf, sqf, cand, cands, N, ncol);

    hipLaunchKernelGGL(rescore_topk, dim3((N + 3) / 4), dim3(256), 0, stream,
                       x, w, sq, cand, cands, (int*)d_out, N, k);
}

// Round 9
// 1149.451 us; speedup vs baseline: 1.2320x; 1.2320x over previous
//
#include <hip/hip_runtime.h>
#include <math.h>

#define DD 512
#define NBLKA 400

#define PM 128          // prefilter tile rows
#define PN 128          // prefilter tile cols
#define KB 32           // k-chunk (one MFMA K per chunk)
#define ASTRIDE 40      // shorts per LDS row: 32 + 8 pad (80 B, 16B-aligned)
#define CSPLIT 6        // column splits -> 474 blocks, all co-resident
#define NC 16           // candidates kept per row per split
#define PBUF 8          // push buffer per row
#define NCTOT (CSPLIT*NC)   // 96 candidates per row total
#define KOUTMAX 16
#define RS_MARGIN 2e-4f     // rescore prune margin (bf16 score err bound ~3e-5)

typedef __attribute__((ext_vector_type(8))) short bf16x8;   // 8 bf16 = 4 VGPR
typedef __attribute__((ext_vector_type(4))) float f32x4;    // MFMA 16x16 accumulator

static __device__ __forceinline__ unsigned short f2bf(float f) {
    unsigned u = __float_as_uint(f);
    u += 0x7fff + ((u >> 16) & 1);      // round-to-nearest-even
    return (unsigned short)(u >> 16);
}

// ---------------- Kernel A1: partial column sums of x^2 (fp64, deterministic) ----------------
__global__ void colsum_partial(const float* __restrict__ x, double* __restrict__ partial,
                               int N, int rows_per_block) {
    int b = blockIdx.x;
    int t = threadIdx.x;
    int r0 = b * rows_per_block;
    int r1 = min(r0 + rows_per_block, N);
    double s0 = 0.0, s1 = 0.0;
    for (int r = r0; r < r1; ++r) {
        float v0 = x[(size_t)r * DD + t];
        float v1 = x[(size_t)r * DD + t + 256];
        s0 += (double)v0 * (double)v0;
        s1 += (double)v1 * (double)v1;
    }
    partial[(size_t)b * DD + t]       = s0;
    partial[(size_t)b * DD + t + 256] = s1;
}

// ---------------- Kernel A2: rn=1/max(sqrt(s),eps) fp64, w=rn*rn fp64 ----------------
__global__ void colnorm_finish(const double* __restrict__ partial, double* __restrict__ rn,
                               double* __restrict__ w, int nblk) {
    int c = threadIdx.x;                 // 512 threads
    double s = 0.0;
    for (int b = 0; b < nblk; ++b) s += partial[(size_t)b * DD + c];
    double n = fmax(sqrt(s), 1e-12);
    double r = 1.0 / n;
    rn[c]  = r;
    w[c]   = r * r;
}

// ---------------- Kernel B: sq[i] fp64, sqf[i] fp32, xnbf[i][:] bf16 ----------------
__global__ void row_sq(const float* __restrict__ x, const double* __restrict__ rn,
                       double* __restrict__ sq, float* __restrict__ sqf,
                       unsigned short* __restrict__ xnbf, int N) {
    int i = blockIdx.x;
    int t = threadIdx.x;
    double a0 = (double)x[(size_t)i * DD + t]       * rn[t];
    double a1 = (double)x[(size_t)i * DD + t + 256] * rn[t + 256];
    xnbf[(size_t)i * DD + t]       = f2bf((float)a0);
    xnbf[(size_t)i * DD + t + 256] = f2bf((float)a1);
    double local = a0 * a0 + a1 * a1;
    __shared__ double red[256];
    red[t] = local;
    __syncthreads();
    for (int off = 128; off > 0; off >>= 1) {
        if (t < off) red[t] += red[t + off];
        __syncthreads();
    }
    if (t == 0) { sq[i] = red[0]; sqf[i] = (float)red[0]; }
}

// ---------------- Kernel C: bf16 MFMA 128x128 prefilter + per-row top-16 ----------------
// Prefetch for chunk kc+1 is issued AFTER the staged-visible barrier of chunk
// kc, so it overlaps the 16 MFMAs + frag reads and is only drained at the
// next chunk's first barrier (the __syncthreads vmcnt(0) drain).
__global__ __launch_bounds__(256, 3) void gemm_prefilter(
    const unsigned short* __restrict__ xnbf,
    const float* __restrict__ sqf, int* __restrict__ cand, float* __restrict__ cands,
    int N, int ntileN)
{
    __shared__ unsigned short A_s[PM][ASTRIDE];   // 10240 B
    __shared__ unsigned short B_s[PN][ASTRIDE];   // 10240 B
    __shared__ float Ls[PM][NC + 1];              // 8704 B
    __shared__ int   Li[PM][NC + 1];              // 8704 B
    __shared__ float Bsc[PM][PBUF + 1];           // 4608 B
    __shared__ int   Bid[PM][PBUF + 1];           // 4608 B
    __shared__ float sqi_s[PM];
    __shared__ float sqj_s[PN];
    __shared__ float thr_s[PM];
    __shared__ int   cnt_s[PM];
    __shared__ int   flag_s;                      // total ~48.2 KB -> 3 blocks/CU

    const int t      = threadIdx.x;
    const int lane15 = t & 15;
    const int quad   = (t >> 4) & 3;
    const int wave   = t >> 6;
    const int wr     = (wave >> 1) * 64;
    const int wc     = (wave & 1) * 64;
    const int row0   = blockIdx.x * PM;
    const int split  = blockIdx.y;

    const int sr0 = t >> 2, sc0 = t & 3;
    const int sr1 = sr0 + 64, sc1 = sc0;
    const int gi0 = row0 + sr0, gi1 = row0 + sr1;

    if (t == 0) flag_s = 0;
    if (t < PM) {
        int i = row0 + t;
        sqi_s[t] = (i < N) ? sqf[i] : 0.f;
        thr_s[t] = __builtin_inff();
        cnt_s[t] = 0;
        for (int m = 0; m < NC; ++m) { Ls[t][m] = __builtin_inff(); Li[t][m] = 0x7fffffff; }
    }

    f32x4 acc[4][4];

    for (int tile = split; tile < ntileN; tile += CSPLIT) {
        int col0 = tile * PN;
        int gj0 = col0 + sr0, gj1 = col0 + sr1;
        __syncthreads();
        if (t < PN) {
            int j = col0 + t;
            sqj_s[t] = (j < N) ? sqf[j] : __builtin_inff();
        }
#pragma unroll
        for (int mt = 0; mt < 4; ++mt)
#pragma unroll
            for (int nt = 0; nt < 4; ++nt)
                acc[mt][nt] = (f32x4){0.f, 0.f, 0.f, 0.f};

        const uint4 zv = make_uint4(0u, 0u, 0u, 0u);
        uint4 va0 = zv, va1 = zv, vb0 = zv, vb1 = zv;
        if (gi0 < N) va0 = *(const uint4*)&xnbf[(size_t)gi0 * DD + sc0 * 8];
        if (gi1 < N) va1 = *(const uint4*)&xnbf[(size_t)gi1 * DD + sc1 * 8];
        if (gj0 < N) vb0 = *(const uint4*)&xnbf[(size_t)gj0 * DD + sc0 * 8];
        if (gj1 < N) vb1 = *(const uint4*)&xnbf[(size_t)gj1 * DD + sc1 * 8];

#pragma unroll 1
        for (int kc = 0; kc < DD; kc += KB) {
            __syncthreads();   // A: prev frag reads done (also drains prefetch loads)
            *(uint4*)&A_s[sr0][(sc0 ^ (sr0 & 3)) * 8] = va0;
            *(uint4*)&A_s[sr1][(sc1 ^ (sr1 & 3)) * 8] = va1;
            *(uint4*)&B_s[sr0][(sc0 ^ (sr0 & 3)) * 8] = vb0;
            *(uint4*)&B_s[sr1][(sc1 ^ (sr1 & 3)) * 8] = vb1;
            __syncthreads();   // B: staged data visible
            // prefetch next chunk NOW: overlaps frag reads + 16 MFMAs,
            // drained only at next iteration's barrier A
            if (kc + KB < DD) {
                int koff = kc + KB;
                va0 = zv; va1 = zv; vb0 = zv; vb1 = zv;
                if (gi0 < N) va0 = *(const uint4*)&xnbf[(size_t)gi0 * DD + koff + sc0 * 8];
                if (gi1 < N) va1 = *(const uint4*)&xnbf[(size_t)gi1 * DD + koff + sc1 * 8];
                if (gj0 < N) vb0 = *(const uint4*)&xnbf[(size_t)gj0 * DD + koff + sc0 * 8];
                if (gj1 < N) vb1 = *(const uint4*)&xnbf[(size_t)gj1 * DD + koff + sc1 * 8];
            }
            bf16x8 af[4], bfg[4];
#pragma unroll
            for (int mt = 0; mt < 4; ++mt) {
                int r = wr + mt * 16 + lane15;
                af[mt] = *(const bf16x8*)&A_s[r][(quad ^ (r & 3)) * 8];
            }
#pragma unroll
            for (int nt = 0; nt < 4; ++nt) {
                int cl = wc + nt * 16 + lane15;
                bfg[nt] = *(const bf16x8*)&B_s[cl][(quad ^ (cl & 3)) * 8];
            }
#pragma unroll
            for (int mt = 0; mt < 4; ++mt)
#pragma unroll
                for (int nt = 0; nt < 4; ++nt)
                    acc[mt][nt] = __builtin_amdgcn_mfma_f32_16x16x32_bf16(
                        af[mt], bfg[nt], acc[mt][nt], 0, 0, 0);
        }
        // scores in place
#pragma unroll
        for (int mt = 0; mt < 4; ++mt)
#pragma unroll
            for (int nt = 0; nt < 4; ++nt)
#pragma unroll
                for (int reg = 0; reg < 4; ++reg) {
                    int rl = wr + mt * 16 + quad * 4 + reg;
                    int cl = wc + nt * 16 + lane15;
                    float g = acc[mt][nt][reg];
                    acc[mt][nt][reg] = (sqi_s[rl] - 2.f * g) + sqj_s[cl];
                }

        // push/merge rounds (race-free 4-barrier protocol, static acc indexing)
        bool tile_edge = (col0 + PN > N);    // only last tile has j>=N lanes
        unsigned long long done = 0ull;
        for (;;) {
#pragma unroll
            for (int mt = 0; mt < 4; ++mt)
#pragma unroll
                for (int reg = 0; reg < 4; ++reg) {
                    const unsigned long long gb =
                        (0x1111ull << reg) << (mt * 16);   // 4 bits of this group
                    int rl = wr + mt * 16 + quad * 4 + reg;
                    float th = thr_s[rl];
                    // group quick-reject (exact: if min > th, all 4 would reject)
                    float gmin = fminf(fminf(acc[mt][0][reg], acc[mt][1][reg]),
                                       fminf(acc[mt][2][reg], acc[mt][3][reg]));
                    if (!tile_edge && gmin > th) { done |= gb; continue; }
                    if ((done & gb) == gb) continue;
#pragma unroll
                    for (int nt = 0; nt < 4; ++nt) {
                        const unsigned long long bit = 1ull << (mt * 16 + nt * 4 + reg);
                        if (!(done & bit)) {
                            float s = acc[mt][nt][reg];
                            int   j = col0 + wc + nt * 16 + lane15;
                            if (j < N && s <= th) {
                                int pos = atomicAdd(&cnt_s[rl], 1);
                                if (pos < PBUF) {
                                    Bsc[rl][pos] = s;
                                    Bid[rl][pos] = j;
                                    done |= bit;
                                }
                            } else {
                                done |= bit;
                            }
                        }
                    }
                }
            if (done != ~0ull) flag_s = 1;
            __syncthreads();                 // B1
            if (t < PM) {
                int c = cnt_s[t];
                if (c > PBUF) c = PBUF;
                cnt_s[t] = 0;
                for (int m = 0; m < c; ++m) {
                    float s = Bsc[t][m];
                    int   j = Bid[t][m];
                    float ws = Ls[t][NC - 1]; int wj = Li[t][NC - 1];
                    if (s < ws || (s == ws && j < wj)) {
                        int pos = NC - 1;
                        while (pos > 0) {
                            float ps = Ls[t][pos - 1]; int pj = Li[t][pos - 1];
                            if (!(s < ps || (s == ps && j < pj))) break;
                            Ls[t][pos] = ps; Li[t][pos] = pj;
                            --pos;
                        }
                        Ls[t][pos] = s; Li[t][pos] = j;
                    }
                }
                thr_s[t] = Ls[t][NC - 1];
            }
            __syncthreads();                 // B2
            int go = flag_s;
            __syncthreads();                 // B3
            if (t == 0) flag_s = 0;
            __syncthreads();                 // B4
            if (!go) break;
        }
    }
    // write this split's candidates (index + bf16 score)
    if (t < PM) {
        int i = row0 + t;
        if (i < N) {
            for (int m = 0; m < NC; ++m) {
                cand [(size_t)i * NCTOT + split * NC + m] = Li[t][m];
                cands[(size_t)i * NCTOT + split * NC + m] = Ls[t][m];
            }
        }
    }
}

// ---------------- Kernel D: pruned exact fp64 rescore + top-k ----------------
// One wave per row. Finds 9th-smallest bf16 score s9b (pivot counting over
// the 96 candidate scores), then fp64-rescores only s <= s9b + RS_MARGIN.
__global__ __launch_bounds__(256) void rescore_topk(
    const float* __restrict__ x, const double* __restrict__ w,
    const double* __restrict__ sq, const int* __restrict__ cand,
    const float* __restrict__ cands, int* __restrict__ out, int N, int k)
{
    __shared__ float Ssc[4][NCTOT];
    int lane = threadIdx.x & 63;
    int wid  = threadIdx.x >> 6;
    int i = blockIdx.x * 4 + wid;
    if (i >= N) return;

    size_t base = (size_t)i * NCTOT;
    // stage scores to LDS (same-wave producers/consumers)
    Ssc[wid][lane] = cands[base + lane];
    if (lane < NCTOT - 64) Ssc[wid][64 + lane] = cands[base + 64 + lane];

    // 9th-smallest via pivot counting: pivots cover all 96 slots
    float p0 = Ssc[wid][lane];
    float p1 = Ssc[wid][64 + (lane & 31)];
    int c0 = 0, c1 = 0;
    for (int m = 0; m < NCTOT; ++m) {
        float s = Ssc[wid][m];
        c0 += (s <= p0); c1 += (s <= p1);
    }
    float best = __builtin_inff();
    if (c0 >= k) best = p0;
    if (c1 >= k && p1 < best) best = p1;
#pragma unroll
    for (int off = 32; off > 0; off >>= 1)
        best = fminf(best, __shfl_xor(best, off, 64));
    float cut = best + RS_MARGIN;

    double aw[8];
#pragma unroll
    for (int c = 0; c < 8; ++c) {
        int d = lane + 64 * c;
        aw[c] = (double)x[(size_t)i * DD + d] * w[d];
    }
    double sqi = sq[i];

    double bs[KOUTMAX];
    int    bj[KOUTMAX];
    for (int r = 0; r < k; ++r) { bs[r] = __builtin_inf(); bj[r] = 0x7fffffff; }

    for (int m = 0; m < NCTOT; ++m) {
        if (Ssc[wid][m] > cut) continue;          // wave-uniform skip
        int j = cand[base + m];
        double dot = 0.0;
        const float* p = &x[(size_t)j * DD + lane];
#pragma unroll
        for (int c = 0; c < 8; ++c)
            dot = fma(aw[c], (double)p[64 * c], dot);
#pragma unroll
        for (int off = 32; off > 0; off >>= 1)
            dot += __shfl_xor(dot, off, 64);
        double s = (sqi - 2.0 * dot) + sq[j];
        if (s < bs[k - 1] || (s == bs[k - 1] && j < bj[k - 1])) {
            int pos = k - 1;
            while (pos > 0) {
                double ps = bs[pos - 1]; int pj = bj[pos - 1];
                if (!(s < ps || (s == ps && j < pj))) break;
                bs[pos] = ps; bj[pos] = pj;
                --pos;
            }
            bs[pos] = s; bj[pos] = j;
        }
    }
    if (lane == 0) {
        for (int r = 0; r < k; ++r) {
            out[(size_t)i * k + r]                 = bj[r];
            out[(size_t)N * k + (size_t)i * k + r] = i;
        }
    }
}

extern "C" void kernel_launch(void* const* d_in, const int* in_sizes, int n_in,
                              void* d_out, int out_size, void* d_ws, size_t ws_size,
                              hipStream_t stream) {
    const float* x = (const float*)d_in[0];
    int N = in_sizes[0] / DD;            // 10000
    int k = out_size / (2 * N);          // 9
    if (k > KOUTMAX) k = KOUTMAX;

    char* ws = (char*)d_ws;
    double*         partial = (double*)ws;                       // 400*512*8 = 1638400 B
    double*         rn      = (double*)(ws + 1638400);           // 4096 B
    double*         w       = (double*)(ws + 1642496);           // 4096 B
    double*         sq      = (double*)(ws + 1646592);           // 80000 B
    float*          sqf     = (float*) (ws + 1726592);           // 40000 B
    unsigned short* xnbf    = (unsigned short*)(ws + 1766592);   // N*512*2 = 10.24 MB
    int*            cand    = (int*)   (ws + 12006592);          // N*96*4 = 3.84 MB
    float*          cands   = (float*) (ws + 15846592);          // N*96*4 = 3.84 MB

    int rpb = (N + NBLKA - 1) / NBLKA;
    hipLaunchKernelGGL(colsum_partial, dim3(NBLKA), dim3(256), 0, stream, x, partial, N, rpb);
    hipLaunchKernelGGL(colnorm_finish, dim3(1), dim3(512), 0, stream, partial, rn, w, NBLKA);
    hipLaunchKernelGGL(row_sq, dim3(N), dim3(256), 0, stream, x, rn, sq, sqf, xnbf, N);

    int nrow = (N + PM - 1) / PM;        // 79
    int ncol = (N + PN - 1) / PN;        // 79
    hipLaunchKernelGGL(gemm_prefilter, dim3(nrow, CSPLIT), dim3(256), 0, stream,
                       xnbf, sqf, cand, cands, N, ncol);

    hipLaunchKernelGGL(rescore_topk, dim3((N + 3) / 4), dim3(256), 0, stream,
                       x, w, sq, cand, cands, (int*)d_out, N, k);
}